// Round 2
// baseline (113.498 us; speedup 1.0000x reference)
//
#include <hip/hip_runtime.h>

// Haar scaling coefficient s = 1/sqrt(2), matching float32(lpf[0]) exactly.
#define HAAR_S 0.70710678118654752440f

// [B=64, H=512, W=512, C=1] fp32 single-level 2D Haar DWT.
// Each thread processes FOUR horizontal 2x2 blocks:
//   reads  : 2x float4 from row 2i and row 2i+1 (2nd load folds to offset:16)
//   writes : one float4 into each of the 4 subband quadrants (16B/lane,
//            lanes j=0..63 write cols 4j..4j+3 -> 1KB contiguous per wave store)
__global__ __launch_bounds__(256) void haar_dwt2d_kernel(
    const float* __restrict__ x, float* __restrict__ out, int batch)
{
    int tid  = blockIdx.x * blockDim.x + threadIdx.x;
    int j    = tid & 63;          // 64 threads per block-row; cols 4j..4j+3 out
    int rest = tid >> 6;
    int i    = rest & 255;        // output row within quadrant (block row)
    int b    = rest >> 8;
    if (b >= batch) return;

    const float* xr0 = x + (size_t)b * (512 * 512) + (size_t)(2 * i) * 512 + 8 * j;
    const float* xr1 = xr0 + 512;
    const float4 p0 = reinterpret_cast<const float4*>(xr0)[0];
    const float4 p1 = reinterpret_cast<const float4*>(xr0)[1];
    const float4 q0 = reinterpret_cast<const float4*>(xr1)[0];
    const float4 q1 = reinterpret_cast<const float4*>(xr1)[1];

    float4 ll, lh, hl, hh;

    // block 0: cols 8j+0,8j+1
    {
        float at = HAAR_S * (p0.x + p0.y), dt = HAAR_S * (p0.x - p0.y);
        float ab = HAAR_S * (q0.x + q0.y), db = HAAR_S * (q0.x - q0.y);
        ll.x = HAAR_S * (at + ab); lh.x = HAAR_S * (at - ab);
        hl.x = HAAR_S * (dt + db); hh.x = HAAR_S * (dt - db);
    }
    // block 1: cols 8j+2,8j+3
    {
        float at = HAAR_S * (p0.z + p0.w), dt = HAAR_S * (p0.z - p0.w);
        float ab = HAAR_S * (q0.z + q0.w), db = HAAR_S * (q0.z - q0.w);
        ll.y = HAAR_S * (at + ab); lh.y = HAAR_S * (at - ab);
        hl.y = HAAR_S * (dt + db); hh.y = HAAR_S * (dt - db);
    }
    // block 2: cols 8j+4,8j+5
    {
        float at = HAAR_S * (p1.x + p1.y), dt = HAAR_S * (p1.x - p1.y);
        float ab = HAAR_S * (q1.x + q1.y), db = HAAR_S * (q1.x - q1.y);
        ll.z = HAAR_S * (at + ab); lh.z = HAAR_S * (at - ab);
        hl.z = HAAR_S * (dt + db); hh.z = HAAR_S * (dt - db);
    }
    // block 3: cols 8j+6,8j+7
    {
        float at = HAAR_S * (p1.z + p1.w), dt = HAAR_S * (p1.z - p1.w);
        float ab = HAAR_S * (q1.z + q1.w), db = HAAR_S * (q1.z - q1.w);
        ll.w = HAAR_S * (at + ab); lh.w = HAAR_S * (at - ab);
        hl.w = HAAR_S * (dt + db); hh.w = HAAR_S * (dt - db);
    }

    float* ob = out + (size_t)b * (512 * 512);
    int c = 4 * j;
    // Quadrant layout: [[ll, hl], [lh, hh]]
    *reinterpret_cast<float4*>(ob + (size_t)i         * 512 + c      ) = ll;
    *reinterpret_cast<float4*>(ob + (size_t)i         * 512 + c + 256) = hl;
    *reinterpret_cast<float4*>(ob + (size_t)(i + 256) * 512 + c      ) = lh;
    *reinterpret_cast<float4*>(ob + (size_t)(i + 256) * 512 + c + 256) = hh;
}

extern "C" void kernel_launch(void* const* d_in, const int* in_sizes, int n_in,
                              void* d_out, int out_size, void* d_ws, size_t ws_size,
                              hipStream_t stream) {
    const float* x = (const float*)d_in[0];
    float* out = (float*)d_out;
    int batch = in_sizes[0] / (512 * 512);       // 64 for this problem
    int total_threads = batch * 256 * 64;        // one thread per four 2x2 blocks
    int block = 256;
    int grid = (total_threads + block - 1) / block;   // 4096 blocks
    haar_dwt2d_kernel<<<grid, block, 0, stream>>>(x, out, batch);
}